// Round 8
// baseline (143.875 us; speedup 1.0000x reference)
//
#include <hip/hip_runtime.h>
#include <hip/hip_bf16.h>

typedef __bf16 bf16;
typedef __bf16 bf16x4 __attribute__((ext_vector_type(4)));
typedef __bf16 bf16x8 __attribute__((ext_vector_type(8)));
typedef float  f32x4  __attribute__((ext_vector_type(4)));

#define BSZ   256
#define SEQ   256
#define DIN   512
#define DEMB  1024
#define KSEL  76
#define MROWS (BSZ * KSEL)   // 19456
#define MT128 (MROWS / 128)  // 152
#define PARTQ (MT128 * 512)
#define NRED  38             // stage-A reduce blocks (152/4)

__device__ __forceinline__ void gload16(const void* g, void* l) {
  __builtin_amdgcn_global_load_lds((const __attribute__((address_space(1))) void*)g,
                                   (__attribute__((address_space(3))) void*)l, 16, 0, 0);
}

// monotone float<->uint order-preserving encode for atomicMax.
// All enc() values are > 0, so zero-init acts as the -inf sentinel
// (every key provably receives >=1 update since plen[b] >= 1).
__device__ __forceinline__ unsigned enc(float v) {
  unsigned u = __float_as_uint(v);
  return (u & 0x80000000u) ? ~u : (u | 0x80000000u);
}
__device__ __forceinline__ float dec(unsigned k) {
  return (k & 0x80000000u) ? __uint_as_float(k ^ 0x80000000u) : __uint_as_float(~k);
}

// ---- fused setup: prep (lengths->topk/plen/keys-init), 3 weight
// transposes (f32 KxN -> bf16 NxK), bias2 = lin_b + b2. Block-role dispatch.
// Roles: [0,256) prep | [256,512) w1 | [512,1024) lin_w | [1024,1536) w2 |
//        [1536,1540) bias2.  Grid = 1540.
__global__ void k_setup(const int* __restrict__ text, int* __restrict__ topk,
                        int* __restrict__ plen, uint4* __restrict__ keys4,
                        const float* __restrict__ w1, bf16* __restrict__ w1t,
                        const float* __restrict__ lin_w, const float* __restrict__ w2,
                        bf16* __restrict__ b2t,
                        const float* __restrict__ lin_b, const float* __restrict__ b2,
                        float* __restrict__ bias2) {
  int blk = blockIdx.x, tid = threadIdx.x;
  if (blk < 256) {
    // prep: atten_sel[b,s] = -1 (s<len) / -0.0 (s>=len); top_k ties -> lowest
    // index first => topk order = [len..255] then [0..] up to k=76.
    int b = blk;
    keys4[b * 256 + tid] = make_uint4(0u, 0u, 0u, 0u);
    __shared__ int red[256];
    red[tid] = (text[b * SEQ + tid] != 0) ? 1 : 0;
    __syncthreads();
    for (int s = 128; s > 0; s >>= 1) {
      if (tid < s) red[tid] += red[tid + s];
      __syncthreads();
    }
    int len = red[0];
    int z = SEQ - len;
    if (tid < KSEL) topk[b * KSEL + tid] = (tid < z) ? (len + tid) : (tid - z);
    if (tid == 0) {
      int p = len - 2;
      plen[b] = p < 1 ? 1 : (p > KSEL ? KSEL : p);
    }
  } else if (blk < 1536) {
    const float* W;
    bf16* Wt;
    int N, ldo, bx, by;
    if (blk < 512)       { int t = blk - 256;  W = w1;    Wt = w1t;       N = 512;  ldo = 512;  bx = t & 15; by = t >> 4; }
    else if (blk < 1024) { int t = blk - 512;  W = lin_w; Wt = b2t;       N = 1024; ldo = 1024; bx = t & 31; by = t >> 5; }
    else                 { int t = blk - 1024; W = w2;    Wt = b2t + 512; N = 1024; ldo = 1024; bx = t & 31; by = t >> 5; }
    __shared__ float tile[32][33];
    int tx = tid & 31, ty = tid >> 5;
    int n = bx * 32 + tx, k0 = by * 32;
#pragma unroll
    for (int r = 0; r < 32; r += 8)
      tile[ty + r][tx] = W[(size_t)(k0 + ty + r) * N + n];
    __syncthreads();
#pragma unroll
    for (int r = 0; r < 32; r += 8)
      Wt[(size_t)(bx * 32 + ty + r) * ldo + k0 + tx] = (bf16)tile[tx][ty + r];
  } else {
    int i = (blk - 1536) * 256 + tid;
    bias2[i] = lin_b[i] + b2[i];
  }
}

// ---- gather + L2 normalize -> bf16 into A2 cols [0,512) ----
__global__ void k_gather(const float* __restrict__ feats, const int* __restrict__ topk,
                         bf16* __restrict__ A2) {
  int r = blockIdx.x;          // 0..19455
  int b = r / KSEL;
  int src = topk[r];
  const float4* row = (const float4*)(feats + ((size_t)b * SEQ + src) * DIN);
  int t = threadIdx.x;         // 128 threads
  float4 v = row[t];
  float ss = v.x * v.x + v.y * v.y + v.z * v.z + v.w * v.w;
#pragma unroll
  for (int o = 32; o > 0; o >>= 1) ss += __shfl_down(ss, o);
  __shared__ float wsum[2];
  if ((t & 63) == 0) wsum[t >> 6] = ss;
  __syncthreads();
  float total = wsum[0] + wsum[1];
  float inv = 1.0f / fmaxf(sqrtf(total), 1e-6f);
  bf16x4 o4;
  o4.x = (bf16)(v.x * inv);
  o4.y = (bf16)(v.y * inv);
  o4.z = (bf16)(v.z * inv);
  o4.w = (bf16)(v.w * inv);
  ((bf16x4*)A2)[(size_t)r * 256 + t] = o4;  // row stride 1024 bf16
}

// fragment read / mfma macros (token-pasted arrays, constant indices only)
#define READF(Af, Bf, buf)                                                        \
  do {                                                                            \
    _Pragma("unroll")                                                             \
    for (int i_ = 0; i_ < 4; ++i_)                                                \
      Af[i_] = *(const bf16x8*)&As[buf][(wr + i_ * 16 + fr) * 32 + fg * 8];       \
    _Pragma("unroll")                                                             \
    for (int j_ = 0; j_ < 4; ++j_)                                                \
      Bf[j_] = *(const bf16x8*)&Bs[buf][(wc + j_ * 16 + fr) * 32 + fg * 8];       \
  } while (0)

#define MFMA16(Af, Bf)                                                            \
  do {                                                                            \
    __builtin_amdgcn_s_setprio(1);                                                \
    _Pragma("unroll")                                                             \
    for (int i_ = 0; i_ < 4; ++i_)                                                \
      _Pragma("unroll")                                                           \
      for (int j_ = 0; j_ < 4; ++j_)                                              \
        acc[i_][j_] = __builtin_amdgcn_mfma_f32_16x16x32_bf16(Af[i_], Bf[j_],     \
                                                              acc[i_][j_], 0, 0, 0); \
    __builtin_amdgcn_s_setprio(0);                                                \
  } while (0)

// ---- 128x128 BK=32 bf16 GEMM, 4 waves, 4 LDS buffers, register-prefetch ----
// Key change vs rounds 5-7 (all 19% MfmaUtil): MFMA(tile t) consumes FRAGMENTS
// READ LAST STEP -> zero wait precedes the MFMA burst; the lgkm(0) for next
// tile's frags hides UNDER the MFMA. Residency publishing is counted: the
// barrier at step t has vmcnt(8) before it (t+3,t+4 newer), guaranteeing tile
// t+2 resident for ALL waves -- never a vmcnt(0) drain in steady state.
// LDS 4 x (A 8KB + B 8KB) = 64KB -> 2 blocks/CU. Linear [128][32] layout
// (2-way bank alias on b128 reads = free, m136).
// EPI=1: bf16 C into Cb + column BN partials. EPI=2: masked per-batch max
// -> global atomicMax on enc() keys (no C write).
template<int EPI>
__global__ __launch_bounds__(256, 2)
void k_gemm(const bf16* __restrict__ A, int lda, const bf16* __restrict__ Bt, int ldb,
            const float* __restrict__ bias, bf16* __restrict__ Cb, int ldc, int Kext,
            int nbx, float* __restrict__ part, const int* __restrict__ plen,
            unsigned* __restrict__ keys) {
  __shared__ __align__(16) bf16 As[4][128 * 32];
  __shared__ __align__(16) bf16 Bs[4][128 * 32];
  // bijective XCD-chunk swizzle (grid % 8 == 0)
  const int q = gridDim.x >> 3;
  const int wg = (blockIdx.x & 7) * q + (blockIdx.x >> 3);
  const int bx = wg % nbx, by = wg / nbx;
  const int m0 = by * 128, n0 = bx * 128;
  const int tid = threadIdx.x, w = tid >> 6, lane = tid & 63;
  const int wr = (w >> 1) * 64, wc = (w & 1) * 64;
  const int srow = lane >> 2, scol = (lane & 3) * 8;   // linear stage layout
  const bf16* Ag0 = A + (size_t)(m0 + w * 16 + srow) * lda + scol;
  const bf16* Ag1 = Ag0 + (size_t)64 * lda;
  const bf16* Bg0 = Bt + (size_t)(n0 + w * 16 + srow) * ldb + scol;
  const bf16* Bg1 = Bg0 + (size_t)64 * ldb;
  const int nT = Kext >> 5;          // BK=32; nT is even (16 or 32)
  f32x4 acc[4][4] = {};
  const int fr = lane & 15, fg = lane >> 4;

  auto stage = [&](int t, int buf) {  // 4 gloads (1KB each)
    const int kt = t << 5;
    gload16(Ag0 + kt, &As[buf][(w * 16) * 32]);
    gload16(Ag1 + kt, &As[buf][(w * 16 + 64) * 32]);
    gload16(Bg0 + kt, &Bs[buf][(w * 16) * 32]);
    gload16(Bg1 + kt, &Bs[buf][(w * 16 + 64) * 32]);
  };

  bf16x8 A0[4], B0[4], A1[4], B1[4];

  // prologue: tiles 0..2 staged; publish t0; read F0; stage t3; publish t1.
  stage(0, 0); stage(1, 1); stage(2, 2);
  asm volatile("s_waitcnt vmcnt(8)" ::: "memory");   // t0 done (t1,t2 = 8 newer)
  __builtin_amdgcn_s_barrier();
  __builtin_amdgcn_sched_barrier(0);
  READF(A0, B0, 0);                                  // frags of tile 0
  stage(3, 3);
  asm volatile("s_waitcnt lgkmcnt(0)" ::: "memory");
  asm volatile("s_waitcnt vmcnt(8)" ::: "memory");   // t1 done (t2,t3 = 8 newer)
  __builtin_amdgcn_s_barrier();
  __builtin_amdgcn_sched_barrier(0);

  for (int t = 0; t < nT; t += 2) {
    // ---- even step: compute tile t (F0); read t+1 -> F1; stage t+4 ----
    if (t + 4 < nT) stage(t + 4, (t + 4) & 3);
    READF(A1, B1, (t + 1) & 3);                      // t+1 published ✓
    __builtin_amdgcn_sched_barrier(0);               // reads issue before MFMA
    MFMA16(A0, B0);                                  // no wait precedes!
    asm volatile("s_waitcnt lgkmcnt(0)" ::: "memory");
    __builtin_amdgcn_sched_barrier(0);
    if (t + 4 < nT)       asm volatile("s_waitcnt vmcnt(8)" ::: "memory");
    else if (t + 3 < nT)  asm volatile("s_waitcnt vmcnt(4)" ::: "memory");
    else                  asm volatile("s_waitcnt vmcnt(0)" ::: "memory");
    __builtin_amdgcn_s_barrier();                    // publish t+2
    __builtin_amdgcn_sched_barrier(0);
    // ---- odd step: compute t+1 (F1); read t+2 -> F0; stage t+5 ----
    if (t + 5 < nT) stage(t + 5, (t + 5) & 3);
    if (t + 2 < nT) READF(A0, B0, (t + 2) & 3);      // t+2 published ✓
    __builtin_amdgcn_sched_barrier(0);
    MFMA16(A1, B1);
    asm volatile("s_waitcnt lgkmcnt(0)" ::: "memory");
    __builtin_amdgcn_sched_barrier(0);
    if (t + 5 < nT)       asm volatile("s_waitcnt vmcnt(8)" ::: "memory");
    else if (t + 4 < nT)  asm volatile("s_waitcnt vmcnt(4)" ::: "memory");
    else                  asm volatile("s_waitcnt vmcnt(0)" ::: "memory");
    __builtin_amdgcn_s_barrier();                    // publish t+3
    __builtin_amdgcn_sched_barrier(0);
  }

  float bv[4];
#pragma unroll
  for (int j = 0; j < 4; ++j) bv[j] = bias[n0 + wc + j * 16 + fr];

  if (EPI == 1) {
    float s[4] = {0, 0, 0, 0}, qq_[4] = {0, 0, 0, 0};
#pragma unroll
    for (int i = 0; i < 4; ++i)
#pragma unroll
      for (int v = 0; v < 4; ++v) {
        int r = m0 + wr + i * 16 + fg * 4 + v;
        bf16* crow = Cb + (size_t)r * ldc + n0 + wc + fr;
#pragma unroll
        for (int j = 0; j < 4; ++j) {
          float val = acc[i][j][v] + bv[j];
          crow[j * 16] = (bf16)val;      // bf16 h_pre into A2 H-half
          s[j] += val;                   // stats stay f32-exact
          qq_[j] += val * val;
        }
      }
    // deterministic reduce over fg (lanes +32, +16), then cross-wave via LDS
#pragma unroll
    for (int j = 0; j < 4; ++j) {
      s[j] += __shfl_down(s[j], 32); s[j] += __shfl_down(s[j], 16);
      qq_[j] += __shfl_down(qq_[j], 32); qq_[j] += __shfl_down(qq_[j], 16);
    }
    __syncthreads();
    float* red = (float*)&As[0][0];  // scratch: [w][j][fr] sums, +256 sq
    if (lane < 16) {
#pragma unroll
      for (int j = 0; j < 4; ++j) {
        red[(w * 4 + j) * 16 + lane] = s[j];
        red[256 + (w * 4 + j) * 16 + lane] = qq_[j];
      }
    }
    __syncthreads();
    if (tid < 128) {
      int c = tid;  // block-local column; waves {c>>6, (c>>6)+2} contributed
      int wsel = c >> 6, jj = (c >> 4) & 3, ff = c & 15;
      float ss = red[(wsel * 4 + jj) * 16 + ff] + red[((wsel + 2) * 4 + jj) * 16 + ff];
      float qs = red[256 + (wsel * 4 + jj) * 16 + ff] +
                 red[256 + ((wsel + 2) * 4 + jj) * 16 + ff];
      part[by * 512 + n0 + c] = ss;
      part[PARTQ + by * 512 + n0 + c] = qs;
    }
  } else {
    const float NEG = -__builtin_huge_valf();
    int cur_b = -1, pl = 0;
    bool any = false;
    float cm[4] = {NEG, NEG, NEG, NEG};
#pragma unroll
    for (int i = 0; i < 4; ++i)
#pragma unroll
      for (int v = 0; v < 4; ++v) {
        int gr = m0 + wr + i * 16 + fg * 4 + v;  // monotone over (i,v)
        int b = gr / KSEL;
        if (b != cur_b) {
          if (any) {
#pragma unroll
            for (int j = 0; j < 4; ++j)
              atomicMax(&keys[(size_t)cur_b * DEMB + n0 + wc + j * 16 + fr], enc(cm[j]));
          }
          cur_b = b;
          pl = plen[b];
          any = false;
#pragma unroll
          for (int j = 0; j < 4; ++j) cm[j] = NEG;
        }
        if (gr - b * KSEL < pl) {
          any = true;
#pragma unroll
          for (int j = 0; j < 4; ++j) cm[j] = fmaxf(cm[j], acc[i][j][v] + bv[j]);
        }
      }
    if (any) {
#pragma unroll
      for (int j = 0; j < 4; ++j)
        atomicMax(&keys[(size_t)cur_b * DEMB + n0 + wc + j * 16 + fr], enc(cm[j]));
    }
  }
}

// ---- BN stats stage A: 38 blocks x 4 tile-rows tree reduce ----
__global__ void k_bnredA(const float* __restrict__ part, float* __restrict__ part2) {
  int i = blockIdx.x, t = threadIdx.x;  // cols 2t, 2t+1
  float s0 = 0, s1 = 0, q0 = 0, q1 = 0;
  for (int j = 0; j < 4; ++j) {
    const float* p = part + (size_t)(i * 4 + j) * 512 + t * 2;
    float2 v = *(const float2*)p;
    float2 u = *(const float2*)(p + PARTQ);
    s0 += v.x; s1 += v.y; q0 += u.x; q1 += u.y;
  }
  part2[i * 512 + t * 2] = s0;
  part2[i * 512 + t * 2 + 1] = s1;
  part2[NRED * 512 + i * 512 + t * 2] = q0;
  part2[NRED * 512 + i * 512 + t * 2 + 1] = q1;
}

// ---- BN stats stage B: scale/shift per column ----
__global__ void k_bnstats(const float* __restrict__ part2, const float* __restrict__ g1,
                          const float* __restrict__ be1, float* __restrict__ bns) {
  int c = threadIdx.x;  // 512
  float s = 0, q = 0;
  for (int i = 0; i < NRED; ++i) {
    s += part2[i * 512 + c];
    q += part2[NRED * 512 + i * 512 + c];
  }
  const float invn = 1.0f / (float)MROWS;
  float mean = s * invn;
  float var = q * invn - mean * mean;  // biased, matches jnp.var
  float sc = rsqrtf(var + 1e-5f) * g1[c];
  bns[c] = sc;
  bns[512 + c] = be1[c] - mean * sc;
}

// ---- BN apply + ReLU, in place on A2 cols [512,1024) (bf16) ----
__global__ void k_bnapply(bf16x8* __restrict__ A2v, const float* __restrict__ bns) {
  size_t idx = (size_t)blockIdx.x * 256 + threadIdx.x;  // 1,245,184 chunks
  size_t row = idx >> 6;
  int c = (int)(idx & 63);                 // 8-col chunk within H half
  bf16x8* p = A2v + row * 128 + 64 + c;    // row stride 1024 bf16 = 128 chunks
  bf16x8 v = *p;
  int c8 = c * 8;
  const float4 s0 = *(const float4*)(bns + c8);
  const float4 s1 = *(const float4*)(bns + c8 + 4);
  const float4 h0 = *(const float4*)(bns + 512 + c8);
  const float4 h1 = *(const float4*)(bns + 512 + c8 + 4);
  bf16x8 o;
  o[0] = (bf16)fmaxf(fmaf((float)v[0], s0.x, h0.x), 0.0f);
  o[1] = (bf16)fmaxf(fmaf((float)v[1], s0.y, h0.y), 0.0f);
  o[2] = (bf16)fmaxf(fmaf((float)v[2], s0.z, h0.z), 0.0f);
  o[3] = (bf16)fmaxf(fmaf((float)v[3], s0.w, h0.w), 0.0f);
  o[4] = (bf16)fmaxf(fmaf((float)v[4], s1.x, h1.x), 0.0f);
  o[5] = (bf16)fmaxf(fmaf((float)v[5], s1.y, h1.y), 0.0f);
  o[6] = (bf16)fmaxf(fmaf((float)v[6], s1.z, h1.z), 0.0f);
  o[7] = (bf16)fmaxf(fmaf((float)v[7], s1.w, h1.w), 0.0f);
  *p = o;
}

// ---- decode pooled keys -> f32 output ----
__global__ void k_decode(const unsigned* __restrict__ keys, float* __restrict__ out) {
  int i = blockIdx.x * 256 + threadIdx.x;
  out[i] = dec(keys[i]);
}

extern "C" void kernel_launch(void* const* d_in, const int* in_sizes, int n_in,
                              void* d_out, int out_size, void* d_ws, size_t ws_size,
                              hipStream_t stream) {
  const float* features = (const float*)d_in[0];
  const int*   text     = (const int*)d_in[1];
  // d_in[2] = atten: provably unused (row eos is overwritten with -1 before use)
  const float* lin_w    = (const float*)d_in[3];
  const float* lin_b    = (const float*)d_in[4];
  const float* w1       = (const float*)d_in[5];
  const float* b1       = (const float*)d_in[6];
  const float* g1       = (const float*)d_in[7];
  const float* be1      = (const float*)d_in[8];
  const float* w2       = (const float*)d_in[9];
  const float* b2       = (const float*)d_in[10];
  float* out = (float*)d_out;
  char* ws = (char*)d_ws;

  // ws layout (bytes)
  int*      topk  = (int*)(ws + 0);           // 77,824
  int*      plen  = (int*)(ws + 77824);       // 1,024
  float*    bns   = (float*)(ws + 78848);     // 4,096 (scale[512], shift[512])
  float*    bias2 = (float*)(ws + 82944);     // 4,096
  float*    part  = (float*)(ws + 87040);     // 622,592 ([2][152][512] f32)
  float*    part2 = (float*)(ws + 709632);    // 155,648 ([2][38][512] f32)
  bf16*     w1t   = (bf16*)(ws + 865280);     // 524,288   (512 x 512)
  bf16*     b2t   = (bf16*)(ws + 1389568);    // 2,097,152 (1024 x 1024: [lin_w ; w2]^T)
  bf16*     A2    = (bf16*)(ws + 3486720);    // 39,845,888 (19456 x 1024: [X | H])
  unsigned* keys  = (unsigned*)(ws + 43332608); // 1,048,576 (256 x 1024 u32)

  k_setup<<<1540, 256, 0, stream>>>(text, topk, plen, (uint4*)keys,
                                    w1, w1t, lin_w, w2, b2t, lin_b, b2, bias2);
  k_gather<<<MROWS, 128, 0, stream>>>(features, topk, A2);
  // H_pre = X @ w1 + b1 -> bf16 into A2[:,512:1024], + fused BN partial stats
  k_gemm<1><<<MT128 * 4, 256, 0, stream>>>(A2, 1024, w1t, 512, b1, A2 + 512, 1024,
                                           512, 4, part, nullptr, nullptr);
  k_bnredA<<<NRED, 256, 0, stream>>>(part, part2);
  k_bnstats<<<1, 512, 0, stream>>>(part2, g1, be1, bns);
  k_bnapply<<<4864, 256, 0, stream>>>((bf16x8*)A2, bns);
  // [X|H] @ [lin_w ; w2] + (lin_b + b2), fused masked max-pool via atomicMax
  k_gemm<2><<<MT128 * 8, 256, 0, stream>>>(A2, 1024, b2t, 1024, bias2, nullptr, 0,
                                           1024, 8, nullptr, plen, keys);
  k_decode<<<BSZ * DEMB / 256, 256, 0, stream>>>(keys, out);
}

// Round 9
// 136.003 us; speedup vs baseline: 1.0579x; 1.0579x over previous
//
#include <hip/hip_runtime.h>
#include <hip/hip_bf16.h>

typedef __bf16 bf16;
typedef __bf16 bf16x4 __attribute__((ext_vector_type(4)));
typedef __bf16 bf16x8 __attribute__((ext_vector_type(8)));
typedef float  f32x4  __attribute__((ext_vector_type(4)));

#define BSZ   256
#define SEQ   256
#define DIN   512
#define DEMB  1024
#define KSEL  76
#define MROWS (BSZ * KSEL)   // 19456
#define MT256 (MROWS / 256)  // 76
#define PART76 (MT256 * 512)
#define NRED  19             // stage-A reduce blocks (76/4)

__device__ __forceinline__ void gload16(const void* g, void* l) {
  __builtin_amdgcn_global_load_lds((const __attribute__((address_space(1))) void*)g,
                                   (__attribute__((address_space(3))) void*)l, 16, 0, 0);
}

// monotone float<->uint order-preserving encode for atomicMax.
// All enc() values are > 0, so zero-init acts as the -inf sentinel
// (every key provably receives >=1 update since plen[b] >= 1).
__device__ __forceinline__ unsigned enc(float v) {
  unsigned u = __float_as_uint(v);
  return (u & 0x80000000u) ? ~u : (u | 0x80000000u);
}
__device__ __forceinline__ float dec(unsigned k) {
  return (k & 0x80000000u) ? __uint_as_float(k ^ 0x80000000u) : __uint_as_float(~k);
}

// ---- fused setup: prep (lengths->topk/plen/keys-init), 3 weight
// transposes (f32 KxN -> bf16 NxK), bias2 = lin_b + b2. Block-role dispatch.
// Roles: [0,256) prep | [256,512) w1 | [512,1024) lin_w | [1024,1536) w2 |
//        [1536,1540) bias2.  Grid = 1540.
__global__ void k_setup(const int* __restrict__ text, int* __restrict__ topk,
                        int* __restrict__ plen, uint4* __restrict__ keys4,
                        const float* __restrict__ w1, bf16* __restrict__ w1t,
                        const float* __restrict__ lin_w, const float* __restrict__ w2,
                        bf16* __restrict__ b2t,
                        const float* __restrict__ lin_b, const float* __restrict__ b2,
                        float* __restrict__ bias2) {
  int blk = blockIdx.x, tid = threadIdx.x;
  if (blk < 256) {
    // prep: atten_sel[b,s] = -1 (s<len) / -0.0 (s>=len); top_k ties -> lowest
    // index first => topk order = [len..255] then [0..] up to k=76.
    int b = blk;
    keys4[b * 256 + tid] = make_uint4(0u, 0u, 0u, 0u);
    __shared__ int red[256];
    red[tid] = (text[b * SEQ + tid] != 0) ? 1 : 0;
    __syncthreads();
    for (int s = 128; s > 0; s >>= 1) {
      if (tid < s) red[tid] += red[tid + s];
      __syncthreads();
    }
    int len = red[0];
    int z = SEQ - len;
    if (tid < KSEL) topk[b * KSEL + tid] = (tid < z) ? (len + tid) : (tid - z);
    if (tid == 0) {
      int p = len - 2;
      plen[b] = p < 1 ? 1 : (p > KSEL ? KSEL : p);
    }
  } else if (blk < 1536) {
    const float* W;
    bf16* Wt;
    int N, ldo, bx, by;
    if (blk < 512)       { int t = blk - 256;  W = w1;    Wt = w1t;       N = 512;  ldo = 512;  bx = t & 15; by = t >> 4; }
    else if (blk < 1024) { int t = blk - 512;  W = lin_w; Wt = b2t;       N = 1024; ldo = 1024; bx = t & 31; by = t >> 5; }
    else                 { int t = blk - 1024; W = w2;    Wt = b2t + 512; N = 1024; ldo = 1024; bx = t & 31; by = t >> 5; }
    __shared__ float tile[32][33];
    int tx = tid & 31, ty = tid >> 5;
    int n = bx * 32 + tx, k0 = by * 32;
#pragma unroll
    for (int r = 0; r < 32; r += 8)
      tile[ty + r][tx] = W[(size_t)(k0 + ty + r) * N + n];
    __syncthreads();
#pragma unroll
    for (int r = 0; r < 32; r += 8)
      Wt[(size_t)(bx * 32 + ty + r) * ldo + k0 + tx] = (bf16)tile[tx][ty + r];
  } else {
    int i = (blk - 1536) * 256 + tid;
    bias2[i] = lin_b[i] + b2[i];
  }
}

// ---- gather + L2 normalize -> bf16 into A2 cols [0,512) ----
__global__ void k_gather(const float* __restrict__ feats, const int* __restrict__ topk,
                         bf16* __restrict__ A2) {
  int r = blockIdx.x;          // 0..19455
  int b = r / KSEL;
  int src = topk[r];
  const float4* row = (const float4*)(feats + ((size_t)b * SEQ + src) * DIN);
  int t = threadIdx.x;         // 128 threads
  float4 v = row[t];
  float ss = v.x * v.x + v.y * v.y + v.z * v.z + v.w * v.w;
#pragma unroll
  for (int o = 32; o > 0; o >>= 1) ss += __shfl_down(ss, o);
  __shared__ float wsum[2];
  if ((t & 63) == 0) wsum[t >> 6] = ss;
  __syncthreads();
  float total = wsum[0] + wsum[1];
  float inv = 1.0f / fmaxf(sqrtf(total), 1e-6f);
  bf16x4 o4;
  o4.x = (bf16)(v.x * inv);
  o4.y = (bf16)(v.y * inv);
  o4.z = (bf16)(v.z * inv);
  o4.w = (bf16)(v.w * inv);
  ((bf16x4*)A2)[(size_t)r * 256 + t] = o4;  // row stride 1024 bf16
}

// ---- 256x128 BK=32 bf16 GEMM, 4 waves x (128x64) wave tile, 3 buffers ----
// THE geometry fix: rounds 1-8 all used 64x64 wave tiles = 8 ds_read_b128 per
// 16 MFMA; the CU-shared LDS read port (not the schedule) capped MfmaUtil at
// ~19%. 128x64 per wave = 12 reads per 32 MFMA (0.375 instr/MFMA) + halved
// stage traffic per FLOP -> LDS port and MFMA pipes near balance (m201 uses
// exactly this per-wave shape at 62% MfmaUtil).
// LDS [rows][32] bf16; 16B-slot p of row R holds k-chunk p ^ (R&3) ^ ((R>>2)&3)
// (pre-swizzled global source, linear gload_lds dest, swizzled read slot) --
// bank enumeration: exact 2-way aliasing = free (m136). Read slot is
// lane-constant: fg ^ (fr&3) ^ ((fr>>2)&3).
// Per tile: stage(t+2) [6 gloads] || 12 ds_read -> lgkm(0) -> 32 MFMA ->
// vmcnt(6) [t+1 resident, t+2 in flight] -> barrier. Never vmcnt(0) drain.
// EPI=1: bf16 C into Cb + column BN partials. EPI=2: masked per-batch max
// -> global atomicMax on enc() keys (no C write).
template<int EPI>
__global__ __launch_bounds__(256, 2)
void k_gemm(const bf16* __restrict__ A, int lda, const bf16* __restrict__ Bt, int ldb,
            const float* __restrict__ bias, bf16* __restrict__ Cb, int ldc, int Kext,
            int nbx, float* __restrict__ part, const int* __restrict__ plen,
            unsigned* __restrict__ keys) {
  __shared__ __align__(16) bf16 As[3][256 * 32];
  __shared__ __align__(16) bf16 Bs[3][128 * 32];
  // bijective XCD-chunk swizzle (grid % 8 == 0)
  const int q = gridDim.x >> 3;
  const int wg = (blockIdx.x & 7) * q + (blockIdx.x >> 3);
  const int bx = wg % nbx, by = wg / nbx;
  const int m0 = by * 256, n0 = bx * 128;
  const int tid = threadIdx.x, w = tid >> 6, lane = tid & 63;
  const int wm = w >> 1, wn = w & 1;          // wave tile: 128 rows x 64 cols
  const int srow = lane >> 2;                 // stage: 16 rows per gload16
  const int scol = (((lane & 3) ^ ((lane >> 2) & 3) ^ ((lane >> 4) & 3))) * 8;
  const bf16* Ag = A + (size_t)(m0 + w * 64 + srow) * lda + scol;
  const bf16* Bg = Bt + (size_t)(n0 + w * 32 + srow) * ldb + scol;
  const int nT = Kext >> 5;                   // BK=32
  f32x4 acc[8][4] = {};
  const int fr = lane & 15, fg = lane >> 4;
  const int sl = (fg ^ (fr & 3) ^ ((fr >> 2) & 3)) * 8;  // read slot (elems)

  auto stage = [&](int t, int buf) {  // 6 gloads: A 4x16 rows, B 2x16 rows
    const int kt = t << 5;
#pragma unroll
    for (int c = 0; c < 4; ++c)
      gload16(Ag + (size_t)(c * 16) * lda + kt, &As[buf][(w * 64 + c * 16) * 32]);
#pragma unroll
    for (int c = 0; c < 2; ++c)
      gload16(Bg + (size_t)(c * 16) * ldb + kt, &Bs[buf][(w * 32 + c * 16) * 32]);
  };

  stage(0, 0);
  stage(1, 1);
  asm volatile("s_waitcnt vmcnt(6)" ::: "memory");   // tile0 landed
  __builtin_amdgcn_s_barrier();
  __builtin_amdgcn_sched_barrier(0);

  for (int t = 0; t < nT; ++t) {
    const int pb = t % 3;
    if (t + 2 < nT) stage(t + 2, (t + 2) % 3);       // into buf of tile t-1
    bf16x8 Af[8], Bf[4];
#pragma unroll
    for (int i = 0; i < 8; ++i)
      Af[i] = *(const bf16x8*)&As[pb][(wm * 128 + i * 16 + fr) * 32 + sl];
#pragma unroll
    for (int j = 0; j < 4; ++j)
      Bf[j] = *(const bf16x8*)&Bs[pb][(wn * 64 + j * 16 + fr) * 32 + sl];
    asm volatile("s_waitcnt lgkmcnt(0)" ::: "memory");
    __builtin_amdgcn_sched_barrier(0);               // rule 18: no MFMA hoist
    __builtin_amdgcn_s_setprio(1);
#pragma unroll
    for (int i = 0; i < 8; ++i)
#pragma unroll
      for (int j = 0; j < 4; ++j)
        acc[i][j] = __builtin_amdgcn_mfma_f32_16x16x32_bf16(Af[i], Bf[j], acc[i][j], 0, 0, 0);
    __builtin_amdgcn_s_setprio(0);
    if (t + 2 < nT) asm volatile("s_waitcnt vmcnt(6)" ::: "memory");  // t+1 resident
    else            asm volatile("s_waitcnt vmcnt(0)" ::: "memory");  // tail drain
    __builtin_amdgcn_s_barrier();                    // publish t+1
    __builtin_amdgcn_sched_barrier(0);
  }

  float bv[4];
#pragma unroll
  for (int j = 0; j < 4; ++j) bv[j] = bias[n0 + wn * 64 + j * 16 + fr];

  if (EPI == 1) {
    float s[4] = {0, 0, 0, 0}, qq_[4] = {0, 0, 0, 0};
#pragma unroll
    for (int i = 0; i < 8; ++i)
#pragma unroll
      for (int v = 0; v < 4; ++v) {
        int r = m0 + wm * 128 + i * 16 + fg * 4 + v;
        bf16* crow = Cb + (size_t)r * ldc + n0 + wn * 64 + fr;
#pragma unroll
        for (int j = 0; j < 4; ++j) {
          float val = acc[i][j][v] + bv[j];
          crow[j * 16] = (bf16)val;      // bf16 h_pre into A2 H-half
          s[j] += val;                   // stats stay f32-exact
          qq_[j] += val * val;
        }
      }
    // deterministic reduce over fg (lanes +32, +16), then cross-wave via LDS
#pragma unroll
    for (int j = 0; j < 4; ++j) {
      s[j] += __shfl_down(s[j], 32); s[j] += __shfl_down(s[j], 16);
      qq_[j] += __shfl_down(qq_[j], 32); qq_[j] += __shfl_down(qq_[j], 16);
    }
    __syncthreads();
    float* red = (float*)&As[0][0];  // scratch: [w][j][fr] sums, +512 sq
    if (lane < 16) {
#pragma unroll
      for (int j = 0; j < 4; ++j) {
        red[(w * 4 + j) * 16 + lane] = s[j];
        red[512 + (w * 4 + j) * 16 + lane] = qq_[j];
      }
    }
    __syncthreads();
    if (tid < 128) {
      int c = tid;  // block-local column; waves {c>>6, (c>>6)+2} contributed
      int wsel = c >> 6, jj = (c >> 4) & 3, ff = c & 15;
      float ss = red[(wsel * 4 + jj) * 16 + ff] + red[((wsel + 2) * 4 + jj) * 16 + ff];
      float qs = red[512 + (wsel * 4 + jj) * 16 + ff] +
                 red[512 + ((wsel + 2) * 4 + jj) * 16 + ff];
      part[by * 512 + n0 + c] = ss;
      part[PART76 + by * 512 + n0 + c] = qs;
    }
  } else {
    const float NEG = -__builtin_huge_valf();
    int cur_b = -1, pl = 0;
    bool any = false;
    float cm[4] = {NEG, NEG, NEG, NEG};
#pragma unroll
    for (int i = 0; i < 8; ++i)
#pragma unroll
      for (int v = 0; v < 4; ++v) {
        int gr = m0 + wm * 128 + i * 16 + fg * 4 + v;  // monotone over (i,v)
        int b = gr / KSEL;
        if (b != cur_b) {
          if (any) {
#pragma unroll
            for (int j = 0; j < 4; ++j)
              atomicMax(&keys[(size_t)cur_b * DEMB + n0 + wn * 64 + j * 16 + fr], enc(cm[j]));
          }
          cur_b = b;
          pl = plen[b];
          any = false;
#pragma unroll
          for (int j = 0; j < 4; ++j) cm[j] = NEG;
        }
        if (gr - b * KSEL < pl) {
          any = true;
#pragma unroll
          for (int j = 0; j < 4; ++j) cm[j] = fmaxf(cm[j], acc[i][j][v] + bv[j]);
        }
      }
    if (any) {
#pragma unroll
      for (int j = 0; j < 4; ++j)
        atomicMax(&keys[(size_t)cur_b * DEMB + n0 + wn * 64 + j * 16 + fr], enc(cm[j]));
    }
  }
}

// ---- BN stats stage A: 19 blocks x 4 tile-rows tree reduce ----
__global__ void k_bnredA(const float* __restrict__ part, float* __restrict__ part2) {
  int i = blockIdx.x, t = threadIdx.x;  // cols 2t, 2t+1
  float s0 = 0, s1 = 0, q0 = 0, q1 = 0;
  for (int j = 0; j < 4; ++j) {
    const float* p = part + (size_t)(i * 4 + j) * 512 + t * 2;
    float2 v = *(const float2*)p;
    float2 u = *(const float2*)(p + PART76);
    s0 += v.x; s1 += v.y; q0 += u.x; q1 += u.y;
  }
  part2[i * 512 + t * 2] = s0;
  part2[i * 512 + t * 2 + 1] = s1;
  part2[NRED * 512 + i * 512 + t * 2] = q0;
  part2[NRED * 512 + i * 512 + t * 2 + 1] = q1;
}

// ---- BN stats stage B: scale/shift per column ----
__global__ void k_bnstats(const float* __restrict__ part2, const float* __restrict__ g1,
                          const float* __restrict__ be1, float* __restrict__ bns) {
  int c = threadIdx.x;  // 512
  float s = 0, q = 0;
  for (int i = 0; i < NRED; ++i) {
    s += part2[i * 512 + c];
    q += part2[NRED * 512 + i * 512 + c];
  }
  const float invn = 1.0f / (float)MROWS;
  float mean = s * invn;
  float var = q * invn - mean * mean;  // biased, matches jnp.var
  float sc = rsqrtf(var + 1e-5f) * g1[c];
  bns[c] = sc;
  bns[512 + c] = be1[c] - mean * sc;
}

// ---- BN apply + ReLU, in place on A2 cols [512,1024) (bf16) ----
__global__ void k_bnapply(bf16x8* __restrict__ A2v, const float* __restrict__ bns) {
  size_t idx = (size_t)blockIdx.x * 256 + threadIdx.x;  // 1,245,184 chunks
  size_t row = idx >> 6;
  int c = (int)(idx & 63);                 // 8-col chunk within H half
  bf16x8* p = A2v + row * 128 + 64 + c;    // row stride 1024 bf16 = 128 chunks
  bf16x8 v = *p;
  int c8 = c * 8;
  const float4 s0 = *(const float4*)(bns + c8);
  const float4 s1 = *(const float4*)(bns + c8 + 4);
  const float4 h0 = *(const float4*)(bns + 512 + c8);
  const float4 h1 = *(const float4*)(bns + 512 + c8 + 4);
  bf16x8 o;
  o[0] = (bf16)fmaxf(fmaf((float)v[0], s0.x, h0.x), 0.0f);
  o[1] = (bf16)fmaxf(fmaf((float)v[1], s0.y, h0.y), 0.0f);
  o[2] = (bf16)fmaxf(fmaf((float)v[2], s0.z, h0.z), 0.0f);
  o[3] = (bf16)fmaxf(fmaf((float)v[3], s0.w, h0.w), 0.0f);
  o[4] = (bf16)fmaxf(fmaf((float)v[4], s1.x, h1.x), 0.0f);
  o[5] = (bf16)fmaxf(fmaf((float)v[5], s1.y, h1.y), 0.0f);
  o[6] = (bf16)fmaxf(fmaf((float)v[6], s1.z, h1.z), 0.0f);
  o[7] = (bf16)fmaxf(fmaf((float)v[7], s1.w, h1.w), 0.0f);
  *p = o;
}

// ---- decode pooled keys -> f32 output ----
__global__ void k_decode(const unsigned* __restrict__ keys, float* __restrict__ out) {
  int i = blockIdx.x * 256 + threadIdx.x;
  out[i] = dec(keys[i]);
}

extern "C" void kernel_launch(void* const* d_in, const int* in_sizes, int n_in,
                              void* d_out, int out_size, void* d_ws, size_t ws_size,
                              hipStream_t stream) {
  const float* features = (const float*)d_in[0];
  const int*   text     = (const int*)d_in[1];
  // d_in[2] = atten: provably unused (row eos is overwritten with -1 before use)
  const float* lin_w    = (const float*)d_in[3];
  const float* lin_b    = (const float*)d_in[4];
  const float* w1       = (const float*)d_in[5];
  const float* b1       = (const float*)d_in[6];
  const float* g1       = (const float*)d_in[7];
  const float* be1      = (const float*)d_in[8];
  const float* w2       = (const float*)d_in[9];
  const float* b2       = (const float*)d_in[10];
  float* out = (float*)d_out;
  char* ws = (char*)d_ws;

  // ws layout (bytes)
  int*      topk  = (int*)(ws + 0);           // 77,824
  int*      plen  = (int*)(ws + 77824);       // 1,024
  float*    bns   = (float*)(ws + 78848);     // 4,096 (scale[512], shift[512])
  float*    bias2 = (float*)(ws + 82944);     // 4,096
  float*    part  = (float*)(ws + 87040);     // 311,296 ([2][76][512] f32)
  float*    part2 = (float*)(ws + 398336);    // 77,824 ([2][19][512] f32)
  bf16*     w1t   = (bf16*)(ws + 476160);     // 524,288   (512 x 512)
  bf16*     b2t   = (bf16*)(ws + 1000448);    // 2,097,152 (1024 x 1024: [lin_w ; w2]^T)
  bf16*     A2    = (bf16*)(ws + 3097600);    // 39,845,888 (19456 x 1024: [X | H])
  unsigned* keys  = (unsigned*)(ws + 42943488); // 1,048,576 (256 x 1024 u32)

  k_setup<<<1540, 256, 0, stream>>>(text, topk, plen, (uint4*)keys,
                                    w1, w1t, lin_w, w2, b2t, lin_b, b2, bias2);
  k_gather<<<MROWS, 128, 0, stream>>>(features, topk, A2);
  // H_pre = X @ w1 + b1 -> bf16 into A2[:,512:1024], + fused BN partial stats
  k_gemm<1><<<MT256 * 4, 256, 0, stream>>>(A2, 1024, w1t, 512, b1, A2 + 512, 1024,
                                           512, 4, part, nullptr, nullptr);
  k_bnredA<<<NRED, 256, 0, stream>>>(part, part2);
  k_bnstats<<<1, 512, 0, stream>>>(part2, g1, be1, bns);
  k_bnapply<<<4864, 256, 0, stream>>>((bf16x8*)A2, bns);
  // [X|H] @ [lin_w ; w2] + (lin_b + b2), fused masked max-pool via atomicMax
  k_gemm<2><<<MT256 * 8, 256, 0, stream>>>(A2, 1024, b2t, 1024, bias2, nullptr, 0,
                                           1024, 8, nullptr, plen, keys);
  k_decode<<<BSZ * DEMB / 256, 256, 0, stream>>>(keys, out);
}

// Round 10
// 110.177 us; speedup vs baseline: 1.3059x; 1.2344x over previous
//
#include <hip/hip_runtime.h>
#include <hip/hip_bf16.h>

typedef __bf16 bf16;
typedef __bf16 bf16x4 __attribute__((ext_vector_type(4)));
typedef __bf16 bf16x8 __attribute__((ext_vector_type(8)));
typedef float  f32x4  __attribute__((ext_vector_type(4)));

#define BSZ   256
#define SEQ   256
#define DIN   512
#define DEMB  1024
#define KSEL  76
#define MROWS (BSZ * KSEL)   // 19456
#define MT128 (MROWS / 128)  // 152
#define PARTQ (MT128 * 512)
#define NRED  38             // stage-A reduce blocks (152/4)

__device__ __forceinline__ void gload16(const void* g, void* l) {
  __builtin_amdgcn_global_load_lds((const __attribute__((address_space(1))) void*)g,
                                   (__attribute__((address_space(3))) void*)l, 16, 0, 0);
}

// monotone float<->uint order-preserving encode for atomicMax.
// All enc() values are > 0, so zero-init acts as the -inf sentinel
// (every key provably receives >=1 update since plen[b] >= 1).
__device__ __forceinline__ unsigned enc(float v) {
  unsigned u = __float_as_uint(v);
  return (u & 0x80000000u) ? ~u : (u | 0x80000000u);
}
__device__ __forceinline__ float dec(unsigned k) {
  return (k & 0x80000000u) ? __uint_as_float(k ^ 0x80000000u) : __uint_as_float(~k);
}

// ---- fused setup: prep (lengths->topk/plen/keys-init), 3 weight
// transposes (f32 KxN -> bf16 NxK), bias2 = lin_b + b2. Block-role dispatch.
// Roles: [0,256) prep | [256,512) w1 | [512,1024) lin_w | [1024,1536) w2 |
//        [1536,1540) bias2.  Grid = 1540.
__global__ void k_setup(const int* __restrict__ text, int* __restrict__ topk,
                        int* __restrict__ plen, uint4* __restrict__ keys4,
                        const float* __restrict__ w1, bf16* __restrict__ w1t,
                        const float* __restrict__ lin_w, const float* __restrict__ w2,
                        bf16* __restrict__ b2t,
                        const float* __restrict__ lin_b, const float* __restrict__ b2,
                        float* __restrict__ bias2) {
  int blk = blockIdx.x, tid = threadIdx.x;
  if (blk < 256) {
    // prep: atten_sel[b,s] = -1 (s<len) / -0.0 (s>=len); top_k ties -> lowest
    // index first => topk order = [len..255] then [0..] up to k=76.
    int b = blk;
    keys4[b * 256 + tid] = make_uint4(0u, 0u, 0u, 0u);
    __shared__ int red[256];
    red[tid] = (text[b * SEQ + tid] != 0) ? 1 : 0;
    __syncthreads();
    for (int s = 128; s > 0; s >>= 1) {
      if (tid < s) red[tid] += red[tid + s];
      __syncthreads();
    }
    int len = red[0];
    int z = SEQ - len;
    if (tid < KSEL) topk[b * KSEL + tid] = (tid < z) ? (len + tid) : (tid - z);
    if (tid == 0) {
      int p = len - 2;
      plen[b] = p < 1 ? 1 : (p > KSEL ? KSEL : p);
    }
  } else if (blk < 1536) {
    const float* W;
    bf16* Wt;
    int N, ldo, bx, by;
    if (blk < 512)       { int t = blk - 256;  W = w1;    Wt = w1t;       N = 512;  ldo = 512;  bx = t & 15; by = t >> 4; }
    else if (blk < 1024) { int t = blk - 512;  W = lin_w; Wt = b2t;       N = 1024; ldo = 1024; bx = t & 31; by = t >> 5; }
    else                 { int t = blk - 1024; W = w2;    Wt = b2t + 512; N = 1024; ldo = 1024; bx = t & 31; by = t >> 5; }
    __shared__ float tile[32][33];
    int tx = tid & 31, ty = tid >> 5;
    int n = bx * 32 + tx, k0 = by * 32;
#pragma unroll
    for (int r = 0; r < 32; r += 8)
      tile[ty + r][tx] = W[(size_t)(k0 + ty + r) * N + n];
    __syncthreads();
#pragma unroll
    for (int r = 0; r < 32; r += 8)
      Wt[(size_t)(bx * 32 + ty + r) * ldo + k0 + tx] = (bf16)tile[tx][ty + r];
  } else {
    int i = (blk - 1536) * 256 + tid;
    bias2[i] = lin_b[i] + b2[i];
  }
}

// ---- gather + L2 normalize -> bf16 into A2 cols [0,512) ----
__global__ void k_gather(const float* __restrict__ feats, const int* __restrict__ topk,
                         bf16* __restrict__ A2) {
  int r = blockIdx.x;          // 0..19455
  int b = r / KSEL;
  int src = topk[r];
  const float4* row = (const float4*)(feats + ((size_t)b * SEQ + src) * DIN);
  int t = threadIdx.x;         // 128 threads
  float4 v = row[t];
  float ss = v.x * v.x + v.y * v.y + v.z * v.z + v.w * v.w;
#pragma unroll
  for (int o = 32; o > 0; o >>= 1) ss += __shfl_down(ss, o);
  __shared__ float wsum[2];
  if ((t & 63) == 0) wsum[t >> 6] = ss;
  __syncthreads();
  float total = wsum[0] + wsum[1];
  float inv = 1.0f / fmaxf(sqrtf(total), 1e-6f);
  bf16x4 o4;
  o4.x = (bf16)(v.x * inv);
  o4.y = (bf16)(v.y * inv);
  o4.z = (bf16)(v.z * inv);
  o4.w = (bf16)(v.w * inv);
  ((bf16x4*)A2)[(size_t)r * 256 + t] = o4;  // row stride 1024 bf16
}

// ---- 128x128 BK=64 bf16 GEMM -- m97/round-1 skeleton, compiler-scheduled ----
// Session evidence (r1 vs r5-r9): the plain __syncthreads K-loop beat every
// hand-asm pipeline (76us w/ C-write vs 81-100us). So: NO inline asm, NO
// setprio, NO sched_barrier -- the compiler emits the waitcnts and 4 blocks/CU
// provide the cross-block overlap (m114). Upgrades over round 1:
//   * BK=64 (half the barrier drains), single 32KB buffer
//   * r5-proven XOR swizzle: LDS 16B-slot s of row R holds k-chunk s^(R&7)
//     (pre-swizzled global source, linear gload_lds dest) -> 0 bank conflicts
//   * __launch_bounds__(256,4): 4 blocks/CU (128KB LDS, 16 waves/CU)
//   * bijective XCD chunk swizzle on the 1D grid (grid % 8 == 0)
// EPI=1: bf16 C into Cb + column BN partials. EPI=2: masked per-batch max
// -> global atomicMax on enc() keys (no C write).
template<int EPI>
__global__ __launch_bounds__(256, 4)
void k_gemm(const bf16* __restrict__ A, int lda, const bf16* __restrict__ Bt, int ldb,
            const float* __restrict__ bias, bf16* __restrict__ Cb, int ldc, int Kext,
            int nbx, float* __restrict__ part, const int* __restrict__ plen,
            unsigned* __restrict__ keys) {
  __shared__ __align__(16) bf16 As[128 * 64];
  __shared__ __align__(16) bf16 Bs[128 * 64];
  const int q = gridDim.x >> 3;
  const int wg = (blockIdx.x & 7) * q + (blockIdx.x >> 3);
  const int bx = wg % nbx, by = wg / nbx;
  const int m0 = by * 128, n0 = bx * 128;
  const int tid = threadIdx.x, w = tid >> 6, lane = tid & 63;
  const int wr = (w >> 1) * 64, wc = (w & 1) * 64;
  const int srow = lane >> 3;                 // 0..7 within an 8-row stage call
  const int scol = ((lane & 7) ^ srow) * 8;   // pre-swizzled source column
  const bf16* Ag = A + (size_t)(m0 + w * 32 + srow) * lda + scol;
  const bf16* Bg = Bt + (size_t)(n0 + w * 32 + srow) * ldb + scol;
  f32x4 acc[4][4] = {};
  const int fr = lane & 15, fg = lane >> 4;

  for (int kt = 0; kt < Kext; kt += 64) {
    __syncthreads();                          // WAR: everyone done reading
#pragma unroll
    for (int c = 0; c < 4; ++c) {
      gload16(Ag + (size_t)(c * 8) * lda + kt, &As[(w * 32 + c * 8) * 64]);
      gload16(Bg + (size_t)(c * 8) * ldb + kt, &Bs[(w * 32 + c * 8) * 64]);
    }
    __syncthreads();                          // compiler emits vmcnt(0) drain
#pragma unroll
    for (int kk = 0; kk < 2; ++kk) {
      const int slot = ((kk << 2) | fg) ^ (fr & 7);
      bf16x8 af[4], bfr[4];
#pragma unroll
      for (int i = 0; i < 4; ++i)
        af[i] = *(const bf16x8*)&As[(wr + i * 16 + fr) * 64 + slot * 8];
#pragma unroll
      for (int j = 0; j < 4; ++j)
        bfr[j] = *(const bf16x8*)&Bs[(wc + j * 16 + fr) * 64 + slot * 8];
#pragma unroll
      for (int i = 0; i < 4; ++i)
#pragma unroll
        for (int j = 0; j < 4; ++j)
          acc[i][j] = __builtin_amdgcn_mfma_f32_16x16x32_bf16(af[i], bfr[j], acc[i][j], 0, 0, 0);
    }
  }

  float bv[4];
#pragma unroll
  for (int j = 0; j < 4; ++j) bv[j] = bias[n0 + wc + j * 16 + fr];

  if (EPI == 1) {
    float s[4] = {0, 0, 0, 0}, qq_[4] = {0, 0, 0, 0};
#pragma unroll
    for (int i = 0; i < 4; ++i)
#pragma unroll
      for (int v = 0; v < 4; ++v) {
        int r = m0 + wr + i * 16 + fg * 4 + v;
        bf16* crow = Cb + (size_t)r * ldc + n0 + wc + fr;
#pragma unroll
        for (int j = 0; j < 4; ++j) {
          float val = acc[i][j][v] + bv[j];
          crow[j * 16] = (bf16)val;      // bf16 h_pre into A2 H-half
          s[j] += val;                   // stats stay f32-exact
          qq_[j] += val * val;
        }
      }
    // deterministic reduce over fg (lanes +32, +16), then cross-wave via LDS
#pragma unroll
    for (int j = 0; j < 4; ++j) {
      s[j] += __shfl_down(s[j], 32); s[j] += __shfl_down(s[j], 16);
      qq_[j] += __shfl_down(qq_[j], 32); qq_[j] += __shfl_down(qq_[j], 16);
    }
    __syncthreads();
    float* red = (float*)&As[0];  // scratch: [w][j][fr] sums, +256 sq
    if (lane < 16) {
#pragma unroll
      for (int j = 0; j < 4; ++j) {
        red[(w * 4 + j) * 16 + lane] = s[j];
        red[256 + (w * 4 + j) * 16 + lane] = qq_[j];
      }
    }
    __syncthreads();
    if (tid < 128) {
      int c = tid;  // block-local column; waves {c>>6, (c>>6)+2} contributed
      int wsel = c >> 6, jj = (c >> 4) & 3, ff = c & 15;
      float ss = red[(wsel * 4 + jj) * 16 + ff] + red[((wsel + 2) * 4 + jj) * 16 + ff];
      float qs = red[256 + (wsel * 4 + jj) * 16 + ff] +
                 red[256 + ((wsel + 2) * 4 + jj) * 16 + ff];
      part[by * 512 + n0 + c] = ss;
      part[PARTQ + by * 512 + n0 + c] = qs;
    }
  } else {
    const float NEG = -__builtin_huge_valf();
    int cur_b = -1, pl = 0;
    bool any = false;
    float cm[4] = {NEG, NEG, NEG, NEG};
#pragma unroll
    for (int i = 0; i < 4; ++i)
#pragma unroll
      for (int v = 0; v < 4; ++v) {
        int gr = m0 + wr + i * 16 + fg * 4 + v;  // monotone over (i,v)
        int b = gr / KSEL;
        if (b != cur_b) {
          if (any) {
#pragma unroll
            for (int j = 0; j < 4; ++j)
              atomicMax(&keys[(size_t)cur_b * DEMB + n0 + wc + j * 16 + fr], enc(cm[j]));
          }
          cur_b = b;
          pl = plen[b];
          any = false;
#pragma unroll
          for (int j = 0; j < 4; ++j) cm[j] = NEG;
        }
        if (gr - b * KSEL < pl) {
          any = true;
#pragma unroll
          for (int j = 0; j < 4; ++j) cm[j] = fmaxf(cm[j], acc[i][j][v] + bv[j]);
        }
      }
    if (any) {
#pragma unroll
      for (int j = 0; j < 4; ++j)
        atomicMax(&keys[(size_t)cur_b * DEMB + n0 + wc + j * 16 + fr], enc(cm[j]));
    }
  }
}

// ---- BN stats stage A: 38 blocks x 4 tile-rows tree reduce ----
__global__ void k_bnredA(const float* __restrict__ part, float* __restrict__ part2) {
  int i = blockIdx.x, t = threadIdx.x;  // cols 2t, 2t+1
  float s0 = 0, s1 = 0, q0 = 0, q1 = 0;
  for (int j = 0; j < 4; ++j) {
    const float* p = part + (size_t)(i * 4 + j) * 512 + t * 2;
    float2 v = *(const float2*)p;
    float2 u = *(const float2*)(p + PARTQ);
    s0 += v.x; s1 += v.y; q0 += u.x; q1 += u.y;
  }
  part2[i * 512 + t * 2] = s0;
  part2[i * 512 + t * 2 + 1] = s1;
  part2[NRED * 512 + i * 512 + t * 2] = q0;
  part2[NRED * 512 + i * 512 + t * 2 + 1] = q1;
}

// ---- BN stats stage B: scale/shift per column ----
__global__ void k_bnstats(const float* __restrict__ part2, const float* __restrict__ g1,
                          const float* __restrict__ be1, float* __restrict__ bns) {
  int c = threadIdx.x;  // 512
  float s = 0, q = 0;
  for (int i = 0; i < NRED; ++i) {
    s += part2[i * 512 + c];
    q += part2[NRED * 512 + i * 512 + c];
  }
  const float invn = 1.0f / (float)MROWS;
  float mean = s * invn;
  float var = q * invn - mean * mean;  // biased, matches jnp.var
  float sc = rsqrtf(var + 1e-5f) * g1[c];
  bns[c] = sc;
  bns[512 + c] = be1[c] - mean * sc;
}

// ---- BN apply + ReLU, in place on A2 cols [512,1024) (bf16) ----
__global__ void k_bnapply(bf16x8* __restrict__ A2v, const float* __restrict__ bns) {
  size_t idx = (size_t)blockIdx.x * 256 + threadIdx.x;  // 1,245,184 chunks
  size_t row = idx >> 6;
  int c = (int)(idx & 63);                 // 8-col chunk within H half
  bf16x8* p = A2v + row * 128 + 64 + c;    // row stride 1024 bf16 = 128 chunks
  bf16x8 v = *p;
  int c8 = c * 8;
  const float4 s0 = *(const float4*)(bns + c8);
  const float4 s1 = *(const float4*)(bns + c8 + 4);
  const float4 h0 = *(const float4*)(bns + 512 + c8);
  const float4 h1 = *(const float4*)(bns + 512 + c8 + 4);
  bf16x8 o;
  o[0] = (bf16)fmaxf(fmaf((float)v[0], s0.x, h0.x), 0.0f);
  o[1] = (bf16)fmaxf(fmaf((float)v[1], s0.y, h0.y), 0.0f);
  o[2] = (bf16)fmaxf(fmaf((float)v[2], s0.z, h0.z), 0.0f);
  o[3] = (bf16)fmaxf(fmaf((float)v[3], s0.w, h0.w), 0.0f);
  o[4] = (bf16)fmaxf(fmaf((float)v[4], s1.x, h1.x), 0.0f);
  o[5] = (bf16)fmaxf(fmaf((float)v[5], s1.y, h1.y), 0.0f);
  o[6] = (bf16)fmaxf(fmaf((float)v[6], s1.z, h1.z), 0.0f);
  o[7] = (bf16)fmaxf(fmaf((float)v[7], s1.w, h1.w), 0.0f);
  *p = o;
}

// ---- decode pooled keys -> f32 output ----
__global__ void k_decode(const unsigned* __restrict__ keys, float* __restrict__ out) {
  int i = blockIdx.x * 256 + threadIdx.x;
  out[i] = dec(keys[i]);
}

extern "C" void kernel_launch(void* const* d_in, const int* in_sizes, int n_in,
                              void* d_out, int out_size, void* d_ws, size_t ws_size,
                              hipStream_t stream) {
  const float* features = (const float*)d_in[0];
  const int*   text     = (const int*)d_in[1];
  // d_in[2] = atten: provably unused (row eos is overwritten with -1 before use)
  const float* lin_w    = (const float*)d_in[3];
  const float* lin_b    = (const float*)d_in[4];
  const float* w1       = (const float*)d_in[5];
  const float* b1       = (const float*)d_in[6];
  const float* g1       = (const float*)d_in[7];
  const float* be1      = (const float*)d_in[8];
  const float* w2       = (const float*)d_in[9];
  const float* b2       = (const float*)d_in[10];
  float* out = (float*)d_out;
  char* ws = (char*)d_ws;

  // ws layout (bytes)
  int*      topk  = (int*)(ws + 0);           // 77,824
  int*      plen  = (int*)(ws + 77824);       // 1,024
  float*    bns   = (float*)(ws + 78848);     // 4,096 (scale[512], shift[512])
  float*    bias2 = (float*)(ws + 82944);     // 4,096
  float*    part  = (float*)(ws + 87040);     // 622,592 ([2][152][512] f32)
  float*    part2 = (float*)(ws + 709632);    // 155,648 ([2][38][512] f32)
  bf16*     w1t   = (bf16*)(ws + 865280);     // 524,288   (512 x 512)
  bf16*     b2t   = (bf16*)(ws + 1389568);    // 2,097,152 (1024 x 1024: [lin_w ; w2]^T)
  bf16*     A2    = (bf16*)(ws + 3486720);    // 39,845,888 (19456 x 1024: [X | H])
  unsigned* keys  = (unsigned*)(ws + 43332608); // 1,048,576 (256 x 1024 u32)

  k_setup<<<1540, 256, 0, stream>>>(text, topk, plen, (uint4*)keys,
                                    w1, w1t, lin_w, w2, b2t, lin_b, b2, bias2);
  k_gather<<<MROWS, 128, 0, stream>>>(features, topk, A2);
  // H_pre = X @ w1 + b1 -> bf16 into A2[:,512:1024], + fused BN partial stats
  k_gemm<1><<<MT128 * 4, 256, 0, stream>>>(A2, 1024, w1t, 512, b1, A2 + 512, 1024,
                                           512, 4, part, nullptr, nullptr);
  k_bnredA<<<NRED, 256, 0, stream>>>(part, part2);
  k_bnstats<<<1, 512, 0, stream>>>(part2, g1, be1, bns);
  k_bnapply<<<4864, 256, 0, stream>>>((bf16x8*)A2, bns);
  // [X|H] @ [lin_w ; w2] + (lin_b + b2), fused masked max-pool via atomicMax
  k_gemm<2><<<MT128 * 8, 256, 0, stream>>>(A2, 1024, b2t, 1024, bias2, nullptr, 0,
                                           1024, 8, nullptr, plen, keys);
  k_decode<<<BSZ * DEMB / 256, 256, 0, stream>>>(keys, out);
}